// Round 5
// baseline (2829.678 us; speedup 1.0000x reference)
//
#include <hip/hip_runtime.h>
#include <stdint.h>

// ---------------------------------------------------------------------------
// Fused SDE sampler, round 7: PHASE-INTERLEAVED HALF-ROW PIPELINE.
//   Round-6 diagnosis: registers (112 weight VGPRs + working set ~ 256/wave)
//   pin occupancy at 2 waves/SIMD regardless of LDS, so the ~30% idle issue
//   slots must be filled with intra-wave ILP.  Rows split into halves H0/H1
//   and the three stages skewed so every barrier region holds TWO independent
//   chunks (disjoint LDS buffers, weights, accumulators):
//     A: L2_n(H0) | L1_n(H1) | draw eta(n,H0)
//     B: L3+upd_n(H0) | L2_n(H1) | draw eta(n,H1)
//     C: L1_{n+1}(H0) | L3+upd_n(H1)
//   Single-buffered LDS verified safe (each half written/read in different
//   regions, barrier between).  L3 ownership remapped: wave w owns row-tile
//   rt=2h+(w&1) per half h, dim-tile w>>1 -> balanced work, identical
//   per-element RNG indices (bit-identical draws).  RNG is one-region-ahead
//   (no cross-step state).  sqrt(2) folded into erfinv coefficients.
//   Weights in registers, fragment-linear LDS, x0-hoist: as round 6.
// ---------------------------------------------------------------------------

#define PARTITIONABLE 1

namespace {

constexpr int   kObs    = 65536;
constexpr int   kDim    = 64;
constexpr int   kSteps  = 64;
constexpr float kDs     = 1.0f / 64.0f;
constexpr float kSqrtDs = 0.125f;

constexpr int kWeightBytes = 256 * 1024;          // 8 waves x 32 tiles x 1 KB
constexpr int kKeysOff     = kWeightBytes;        // uint32[2][64][2] = 1 KB
constexpr int kStabOff     = kKeysOff + 1024;     // f32x4[64]        = 1 KB

typedef _Float16 f16x8 __attribute__((ext_vector_type(8)));
typedef _Float16 f16x4 __attribute__((ext_vector_type(4)));
typedef float    f32x4 __attribute__((ext_vector_type(4)));

#define MFMA16(a, b, c) __builtin_amdgcn_mfma_f32_16x16x32_f16((a), (b), (c), 0, 0, 0)

__device__ __forceinline__ uint32_t rotl(uint32_t v, int r) {
  return (v << r) | (v >> (32 - r));
}

__device__ __forceinline__ void tf2x32(uint32_t k0, uint32_t k1,
                                       uint32_t& x0, uint32_t& x1) {
  uint32_t k2 = k0 ^ k1 ^ 0x1BD11BDAu;
  x0 += k0; x1 += k1;
  x0 += x1; x1 = rotl(x1, 13); x1 ^= x0;
  x0 += x1; x1 = rotl(x1, 15); x1 ^= x0;
  x0 += x1; x1 = rotl(x1, 26); x1 ^= x0;
  x0 += x1; x1 = rotl(x1,  6); x1 ^= x0;
  x0 += k1; x1 += k2 + 1u;
  x0 += x1; x1 = rotl(x1, 17); x1 ^= x0;
  x0 += x1; x1 = rotl(x1, 29); x1 ^= x0;
  x0 += x1; x1 = rotl(x1, 16); x1 ^= x0;
  x0 += x1; x1 = rotl(x1, 24); x1 ^= x0;
  x0 += k2; x1 += k0 + 2u;
  x0 += x1; x1 = rotl(x1, 13); x1 ^= x0;
  x0 += x1; x1 = rotl(x1, 15); x1 ^= x0;
  x0 += x1; x1 = rotl(x1, 26); x1 ^= x0;
  x0 += x1; x1 = rotl(x1,  6); x1 ^= x0;
  x0 += k0; x1 += k1 + 3u;
  x0 += x1; x1 = rotl(x1, 17); x1 ^= x0;
  x0 += x1; x1 = rotl(x1, 29); x1 ^= x0;
  x0 += x1; x1 = rotl(x1, 16); x1 ^= x0;
  x0 += x1; x1 = rotl(x1, 24); x1 ^= x0;
  x0 += k1; x1 += k2 + 4u;
  x0 += x1; x1 = rotl(x1, 13); x1 ^= x0;
  x0 += x1; x1 = rotl(x1, 15); x1 ^= x0;
  x0 += x1; x1 = rotl(x1, 26); x1 ^= x0;
  x0 += x1; x1 = rotl(x1,  6); x1 ^= x0;
  x0 += k2; x1 += k0 + 5u;
}

__device__ __forceinline__ void jax_split(uint32_t k0, uint32_t k1,
                                          uint32_t& a0, uint32_t& a1,
                                          uint32_t& b0, uint32_t& b1) {
#if PARTITIONABLE
  uint32_t x0 = 0u, x1 = 0u; tf2x32(k0, k1, x0, x1); a0 = x0; a1 = x1;
  uint32_t y0 = 0u, y1 = 1u; tf2x32(k0, k1, y0, y1); b0 = y0; b1 = y1;
#else
  uint32_t x0 = 0u, x1 = 2u; tf2x32(k0, k1, x0, x1);
  uint32_t y0 = 1u, y1 = 3u; tf2x32(k0, k1, y0, y1);
  a0 = x0; a1 = y0; b0 = x1; b1 = y1;
#endif
}

__device__ __forceinline__ uint32_t draw_bits(uint32_t k0, uint32_t k1, uint32_t i) {
#if PARTITIONABLE
  uint32_t x0 = 0u, x1 = i;
  tf2x32(k0, k1, x0, x1);
  return x0 ^ x1;
#else
  const uint32_t half = (uint32_t)kObs * kDim / 2;
  if (i < half) {
    uint32_t x0 = i, x1 = i + half; tf2x32(k0, k1, x0, x1); return x0;
  } else {
    uint32_t x0 = i - half, x1 = i; tf2x32(k0, k1, x0, x1); return x1;
  }
#endif
}

// returns sqrt(2)*erfinv(x): sqrt(2) folded into the polynomial coefficients
__device__ __forceinline__ float erfinv32s(float x) {
  float w = -__logf(fmaf(-x, x, 1.0f));
  float p;
  if (w < 5.0f) {
    w = w - 2.5f;
    p =            3.974239e-08f;
    p = fmaf(p, w, 4.854653e-07f);
    p = fmaf(p, w, -4.982823e-06f);
    p = fmaf(p, w, -6.210533e-06f);
    p = fmaf(p, w, 3.091202e-04f);
    p = fmaf(p, w, -1.773035e-03f);
    p = fmaf(p, w, -5.908134e-03f);
    p = fmaf(p, w, 3.488027e-01f);
    p = fmaf(p, w, 2.1233135f);
  } else {
    w = sqrtf(w) - 3.0f;
    p =            -2.8314694e-04f;
    p = fmaf(p, w, 1.4276561e-04f);
    p = fmaf(p, w, 1.908261e-03f);
    p = fmaf(p, w, -5.1950111e-03f);
    p = fmaf(p, w, 8.1168903e-03f);
    p = fmaf(p, w, -1.07797888e-02f);
    p = fmaf(p, w, 1.33485780e-02f);
    p = fmaf(p, w, 1.4165811f);
    p = fmaf(p, w, 4.0064343f);
  }
  return p * x;
}

__device__ __forceinline__ float bits_to_normal(uint32_t bits) {
  const float lo = -0.99999994f;
  float f = __uint_as_float(0x3f800000u | (bits >> 9)) - 1.0f;
  float u = fmaxf(lo, fmaf(f, 2.0f, lo));
  return erfinv32s(u);
}

}  // namespace

// ---------------------------------------------------------------------------
// Weight prep: per-wave contiguous fragment tiles + RNG/step tables.
// (identical to round 6 — verified)
// ---------------------------------------------------------------------------
__global__ void prep_weights(const float* __restrict__ W1,
                             const float* __restrict__ W2,
                             const float* __restrict__ W3,
                             _Float16* __restrict__ ws) {
  const int G = blockIdx.x;
  const int t = threadIdx.x;

  if (G >= 256) {
    if (t < 2) {
      uint32_t* kout = (uint32_t*)((char*)ws + kKeysOff) + t * 128;
      uint32_t s0a, s0b, s1a, s1b;
      jax_split(0u, 1u, s0a, s0b, s1a, s1b);
      const uint32_t sk0 = t ? s1a : s0a;
      const uint32_t sk1 = t ? s1b : s0b;
      uint32_t kd0, kd1, kl0, kl1;
      jax_split(sk0, sk1, kd0, kd1, kl0, kl1);
      kout[0] = kd0; kout[1] = kd1;
      for (int n = 1; n < kSteps; ++n) {
        uint32_t na, nb, xa, xb;
        jax_split(kl0, kl1, na, nb, xa, xb);
        kl0 = na; kl1 = nb;
        kout[2 * n] = xa; kout[2 * n + 1] = xb;
      }
    }
    if (t < kSteps) {
      const float s  = (float)t * kDs;
      const float sg = 1.0f - s;
      f32x4 v;
      v[0] = s;
      v[1] = (t == 0) ? 0.0f : 1.0f / (s * sg);
      v[2] = 0.5f * (1.0f - sg * sg);
      v[3] = kDs * v[2] * v[1];                    // P = ds*coef*A
      *(f32x4*)((char*)ws + kStabOff + t * 16) = v;
    }
    return;
  }

  const int lane = t >> 2;
  const int j0   = (t & 3) * 2;
  const int w    = G >> 5;
  const int T    = G & 31;
  const int lm   = lane & 15;
  const int kb   = (lane >> 4) << 3;

#pragma unroll
  for (int jj = 0; jj < 2; ++jj) {
    const int j = j0 + jj;
    float v;
    if (T < 8) {
      const int mt = T >> 2, kt = T & 3;
      const int col = w * 32 + mt * 16 + lm;
      const int k   = kt * 32 + kb + j;          // 0..127 : [x | x0] rows of W1
      v = W1[k * 256 + col];
    } else if (T < 24) {
      const int u = T - 8;
      const int mt = u >> 3, kt = u & 7;
      const int col = w * 32 + mt * 16 + lm;
      const int k   = kt * 32 + kb + j;
      v = W2[k * 256 + col];
    } else {
      const int kt  = T - 24;
      const int col = (w >> 1) * 16 + lm;        // L3 dim-tile = w>>1
      const int k   = kt * 32 + kb + j;
      v = W3[k * 64 + col];
    }
    ws[(size_t)G * 512 + lane * 8 + j] = (_Float16)v;
  }
}

// ---------------------------------------------------------------------------
// Main fused kernel: register weights, fragment LDS, half-row pipeline.
// ---------------------------------------------------------------------------
__global__ __launch_bounds__(512, 2)
void sde_mfma(const float* __restrict__ X0g,
              const float* __restrict__ W1,
              const float* __restrict__ b1,
              const float* __restrict__ b2,
              const float* __restrict__ b3,
              const _Float16* __restrict__ ws,
              float* __restrict__ out) {
  // Fragment-tile LDS: tile(kt,nt) = 1KB; elem (k,n) -> lane'=((k&31)>>3)*16
  // + (n&15), byte lane'*16 + (k&7)*2.  Consumer b128 read = tile + l*16.
  // Tile id = ktile*4 + rowtile.  Half h owns rowtiles {2h, 2h+1}.
  __shared__ alignas(16) char  xAf [8 * 1024];
  __shared__ alignas(16) char  h1f [32 * 1024];   // x0-scratch during init
  __shared__ alignas(16) char  h2f [32 * 1024];
  __shared__ alignas(16) float bb  [832];         // b1|W1s|b2 (256 ea) | b3(64)

  const int t    = threadIdx.x;
  const int w    = t >> 6;                 // wave 0..7: neurons [32w,32w+32)
  const int l    = t & 63;
  const int lq   = l >> 4;
  const int lm   = l & 15;
  const int samp = blockIdx.x >> 10;       // 1024 blocks per sample
  const int tile = blockIdx.x & 1023;
  const int r0   = tile * 64;
  const int mt3  = w >> 1;                 // L3 dim-tile
  const int rpar = w & 1;                  // row-tile parity within each half
  const int d0   = mt3 * 16 + lq * 4;      // this lane's 4 dims

  const int rb  = l * 16;                                    // consumer read
  const int lo1 = ((lq >> 1) * 16 + lm) * 16 + (lq & 1) * 8; // producer (mt=0)
  const int kt3 = mt3 >> 1;
  const int ln3 = (((mt3 & 1) * 2 + (lq >> 1)) * 16 + lm) * 16 + (lq & 1) * 8;

  // ---- stage biases + s-row of W1 ----
  if (t < 256) {
    bb[t]       = b1[t];
    bb[256 + t] = W1[128 * 256 + t];
    bb[512 + t] = b2[t];
  } else if (t < 320) {
    bb[768 + (t - 256)] = b3[t - 256];
  }

  // ---- stage X0 into fragment layout: xAf (live) + h1f (hoist scratch) ----
  {
    const int li = t >> 3;                 // row 0..63
    const int ci = (t & 7) * 8;            // dim base
    const float* p = X0g + (size_t)(r0 + li) * kDim + ci;
    const float4 a = *(const float4*)p;
    const float4 b = *(const float4*)(p + 4);
    f16x8 h;
    h[0] = (_Float16)a.x; h[1] = (_Float16)a.y;
    h[2] = (_Float16)a.z; h[3] = (_Float16)a.w;
    h[4] = (_Float16)b.x; h[5] = (_Float16)b.y;
    h[6] = (_Float16)b.z; h[7] = (_Float16)b.w;
    const int fa = ((ci >> 5) * 4 + (li >> 4)) * 1024 +
                   (((ci >> 3) & 3) * 16 + (li & 15)) * 16;
    *(f16x8*)(xAf + fa) = h;
    *(f16x8*)(h1f + fa) = h;
  }

  // ---- own state: rows (2h+rpar)*16+lm, dims d0..d0+3, h in {0,1} ----
  float xv[2][4];
  f32x4 x0q[2];
#pragma unroll
  for (int h = 0; h < 2; ++h) {
    const int row = (2 * h + rpar) * 16 + lm;
    x0q[h] = *(const f32x4*)(X0g + (size_t)(r0 + row) * kDim + d0);
#pragma unroll
    for (int q = 0; q < 4; ++q) xv[h][q] = x0q[h][q];
  }
  const uint32_t giH0 = (uint32_t)((r0 + rpar * 16 + lm) * kDim + d0);
  const uint32_t giH1 = giH0 + 32u * kDim;

  // ---- preload weight fragments (112 regs) + transient x0-part ----
  const char* pW = (const char*)ws + (size_t)w * 32768 + l * 16;
  f16x8 wL1[2][2], wx0[2][2], wL2[16], wL3[8];
#pragma unroll
  for (int mt = 0; mt < 2; ++mt) {
    wL1[mt][0] = *(const f16x8*)(pW + (mt * 4 + 0) * 1024);
    wL1[mt][1] = *(const f16x8*)(pW + (mt * 4 + 1) * 1024);
    wx0[mt][0] = *(const f16x8*)(pW + (mt * 4 + 2) * 1024);
    wx0[mt][1] = *(const f16x8*)(pW + (mt * 4 + 3) * 1024);
  }
#pragma unroll
  for (int i = 0; i < 16; ++i) wL2[i] = *(const f16x8*)(pW + (8 + i) * 1024);
#pragma unroll
  for (int i = 0; i < 8; ++i)  wL3[i] = *(const f16x8*)(pW + (24 + i) * 1024);

  const uint32_t* keys = (const uint32_t*)((const char*)ws + kKeysOff) + samp * 128;
  const f32x4*    stab = (const f32x4*)((const char*)ws + kStabOff);

  __syncthreads();

  // ---- hoist: pre[nt][mt] = W1[x0 rows]·x0 (step-invariant) ----
  f16x4 pre[4][2];
#pragma unroll
  for (int nt = 0; nt < 4; ++nt) {
    const f16x8 xf0 = *(const f16x8*)(h1f + (0 * 4 + nt) * 1024 + rb);
    const f16x8 xf1 = *(const f16x8*)(h1f + (1 * 4 + nt) * 1024 + rb);
#pragma unroll
    for (int mt = 0; mt < 2; ++mt) {
      f32x4 p = {0.f, 0.f, 0.f, 0.f};
      p = MFMA16(wx0[mt][0], xf0, p);
      p = MFMA16(wx0[mt][1], xf1, p);
      f16x4 ph;
#pragma unroll
      for (int q = 0; q < 4; ++q) ph[q] = (_Float16)p[q];
      pre[nt][mt] = ph;
    }
  }
  __syncthreads();   // scratch reads done before L1 overwrites h1f

  // ---- stage chunks ----
  auto L1C = [&](int h, float sv) {            // L1 for half h, writes h1f(h)
#pragma unroll
    for (int j = 0; j < 2; ++j) {
      const int nt = 2 * h + j;
      const f16x8 bf0 = *(const f16x8*)(xAf + (0 * 4 + nt) * 1024 + rb);
      const f16x8 bf1 = *(const f16x8*)(xAf + (1 * 4 + nt) * 1024 + rb);
#pragma unroll
      for (int mt = 0; mt < 2; ++mt) {
        f32x4 c = {0.f, 0.f, 0.f, 0.f};
        c = MFMA16(wL1[mt][0], bf0, c);
        c = MFMA16(wL1[mt][1], bf1, c);
        const int nb = w * 32 + mt * 16 + lq * 4;
        const f32x4 bq = *(const f32x4*)&bb[nb];
        const f32x4 wq = *(const f32x4*)&bb[256 + nb];
        const f16x4 ph = pre[nt][mt];
        f16x4 o;
#pragma unroll
        for (int q = 0; q < 4; ++q)
          o[q] = (_Float16)fmaxf(c[q] + (float)ph[q] + fmaf(sv, wq[q], bq[q]), 0.f);
        *(f16x4*)(h1f + (w * 4 + nt) * 1024 + mt * 512 + lo1) = o;
      }
    }
  };

  auto L2C = [&](int h) {                      // L2 for half h, h1f(h)->h2f(h)
    f32x4 c[2][2];
#pragma unroll
    for (int mt = 0; mt < 2; ++mt)
#pragma unroll
      for (int ni = 0; ni < 2; ++ni)
        c[mt][ni] = (f32x4){0.f, 0.f, 0.f, 0.f};
#pragma unroll
    for (int kh = 0; kh < 2; ++kh) {
      f16x8 bh[2][4];
#pragma unroll
      for (int ni = 0; ni < 2; ++ni)
#pragma unroll
        for (int k4 = 0; k4 < 4; ++k4)
          bh[ni][k4] = *(const f16x8*)
              (h1f + ((kh * 4 + k4) * 4 + 2 * h + ni) * 1024 + rb);
#pragma unroll
      for (int mt = 0; mt < 2; ++mt)
#pragma unroll
        for (int k4 = 0; k4 < 4; ++k4) {
          const f16x8 aW = wL2[mt * 8 + kh * 4 + k4];
          c[mt][0] = MFMA16(aW, bh[0][k4], c[mt][0]);
          c[mt][1] = MFMA16(aW, bh[1][k4], c[mt][1]);
        }
    }
#pragma unroll
    for (int mt = 0; mt < 2; ++mt) {
      const int nb = w * 32 + mt * 16 + lq * 4;
      const f32x4 bq = *(const f32x4*)&bb[512 + nb];
#pragma unroll
      for (int ni = 0; ni < 2; ++ni) {
        f16x4 o;
#pragma unroll
        for (int q = 0; q < 4; ++q)
          o[q] = (_Float16)fmaxf(c[mt][ni][q] + bq[q], 0.f);
        *(f16x4*)(h2f + (w * 4 + 2 * h + ni) * 1024 + mt * 512 + lo1) = o;
      }
    }
  };

  auto L3U = [&](int h, const float* eta, float sv, float Pv) {
    const int rt = 2 * h + rpar;               // this wave's row-tile in half h
    f32x4 dA = {0.f, 0.f, 0.f, 0.f}, dB = {0.f, 0.f, 0.f, 0.f};
#pragma unroll
    for (int kh = 0; kh < 2; ++kh) {
      f16x8 bh[4];
#pragma unroll
      for (int k4 = 0; k4 < 4; ++k4)
        bh[k4] = *(const f16x8*)(h2f + ((kh * 4 + k4) * 4 + rt) * 1024 + rb);
      dA = MFMA16(wL3[kh * 4 + 0], bh[0], dA);
      dB = MFMA16(wL3[kh * 4 + 1], bh[1], dB);
      dA = MFMA16(wL3[kh * 4 + 2], bh[2], dA);
      dB = MFMA16(wL3[kh * 4 + 3], bh[3], dB);
    }
    const f32x4 b3q = *(const f32x4*)&bb[768 + d0];
    f16x4 hx;
#pragma unroll
    for (int q = 0; q < 4; ++q) {
      const float ov = dA[q] + dB[q] + b3q[q];
      const float t1 = fmaf(sv, ov, x0q[h][q] - xv[h][q]);
      float nx = fmaf(kSqrtDs, eta[q], xv[h][q]);
      nx = fmaf(kDs, ov, nx);
      nx = fmaf(Pv, t1, nx);
      xv[h][q] = nx;
      hx[q] = (_Float16)nx;
    }
    *(f16x4*)(xAf + (kt3 * 4 + rt) * 1024 + ln3) = hx;
  };

  // ---- pipeline prologue: L1_0(H0) ----
  L1C(0, stab[0][0]);
  __syncthreads();

  float et0[4], et1[4];
  for (int n = 0; n < kSteps; ++n) {
    const f32x4 st = stab[n];
    const float s = st[0], P = st[3];
    const uint32_t ka = keys[2 * n], kb = keys[2 * n + 1];

    // ---- region A: L2_n(H0) | L1_n(H1) | eta(n,H0) ----
    L2C(0);
    L1C(1, s);
#pragma unroll
    for (int q = 0; q < 4; ++q)
      et0[q] = bits_to_normal(draw_bits(ka, kb, giH0 + q));
    __syncthreads();

    // ---- region B: L3+upd_n(H0) | L2_n(H1) | eta(n,H1) ----
    L2C(1);
    L3U(0, et0, s, P);
#pragma unroll
    for (int q = 0; q < 4; ++q)
      et1[q] = bits_to_normal(draw_bits(ka, kb, giH1 + q));
    __syncthreads();

    // ---- region C: L1_{n+1}(H0) | L3+upd_n(H1) ----
    if (n + 1 < kSteps) L1C(0, stab[n + 1][0]);
    L3U(1, et1, s, P);
    __syncthreads();
  }

  // ---- write result (each lane owns its 8 elements) ----
#pragma unroll
  for (int h = 0; h < 2; ++h) {
    const int row = (2 * h + rpar) * 16 + lm;
    const size_t ob = (size_t)samp * ((size_t)kObs * kDim) +
                      (size_t)(r0 + row) * kDim + d0;
    f32x4 v;
#pragma unroll
    for (int q = 0; q < 4; ++q) v[q] = xv[h][q];
    *(f32x4*)(out + ob) = v;
  }
}

extern "C" void kernel_launch(void* const* d_in, const int* in_sizes, int n_in,
                              void* d_out, int out_size, void* d_ws, size_t ws_size,
                              hipStream_t stream) {
  const float* X0 = (const float*)d_in[0];
  const float* W1 = (const float*)d_in[1];
  const float* b1 = (const float*)d_in[2];
  const float* W2 = (const float*)d_in[3];
  const float* b2 = (const float*)d_in[4];
  const float* W3 = (const float*)d_in[5];
  const float* b3 = (const float*)d_in[6];
  _Float16* ws = (_Float16*)d_ws;   // 256 KB fragments + 2 KB key/scalar tables

  prep_weights<<<dim3(257), dim3(256), 0, stream>>>(W1, W2, W3, ws);
  sde_mfma<<<dim3(2048), dim3(512), 0, stream>>>(X0, W1, b1, b2, b3, ws,
                                                 (float*)d_out);
}